// Round 1
// baseline (269.217 us; speedup 1.0000x reference)
//
#include <hip/hip_runtime.h>

#define BB 1024
#define TT 1024
#define KQ 15
#define KT 20
#define NDOF 7

// Output layout (flat float offsets, in reference return order)
#define OFF_MODEL 0
#define OFF_QDL   1
#define OFF_QDDL  (1 + BB*NDOF)
#define OFF_QDDDL (1 + 2*BB*NDOF)
#define OFF_TQL   (1 + 3*BB*NDOF)
#define OFF_Q     (1 + 4*BB*NDOF)
#define OFF_QD    (OFF_Q    + (size_t)BB*TT*NDOF)
#define OFF_QDD   (OFF_QD   + (size_t)BB*TT*NDOF)
#define OFF_QDDD  (OFF_QDD  + (size_t)BB*TT*NDOF)
#define OFF_TQ    (OFF_QDDD + (size_t)BB*TT*NDOF)
#define OFF_T     (OFF_TQ   + (size_t)BB*TT*NDOF)
#define OFF_TCUM  (OFF_T    + (size_t)BB)
#define OFF_DT    (OFF_TCUM + (size_t)BB*TT)

__device__ __forceinline__ float hub(float v, float lim) {
    // huber(relu(|v| - lim)), delta = 1.0
    float x = fabsf(v) - lim;
    x = fmaxf(x, 0.0f);
    return (x < 1.0f) ? 0.5f * x * x : (x - 0.5f);
}

__global__ __launch_bounds__(256) void feas_main(
    const float* __restrict__ q_cps, const float* __restrict__ t_cps,
    const float* __restrict__ Nb,  const float* __restrict__ dNb,
    const float* __restrict__ ddNb, const float* __restrict__ dddNb,
    const float* __restrict__ Ntb, const float* __restrict__ dNtb,
    const float* __restrict__ ddNtb,
    const float* __restrict__ qd_lim, const float* __restrict__ qdd_lim,
    const float* __restrict__ qddd_lim,
    float* __restrict__ out)
{
    const int b   = blockIdx.x;
    const int tid = threadIdx.x;

    __shared__ float cps[KQ * NDOF];   // q_cps[b]
    __shared__ float tcs[KT];          // t_cps[b]
    __shared__ float lim[3 * NDOF];    // qd / qdd / qddd limits
    __shared__ float dts[TT];          // per-t dt for scan
    __shared__ float seg[256];         // segment sums for scan
    __shared__ float wred[4 * 21];     // per-wave loss partials

    if (tid < KQ * NDOF)               cps[tid]        = q_cps[(size_t)b * KQ * NDOF + tid];
    if (tid >= 128 && tid < 128 + KT)  tcs[tid - 128]  = t_cps[(size_t)b * KT + (tid - 128)];
    if (tid >= 160 && tid < 160 + NDOF) {
        int d = tid - 160;
        lim[d]          = qd_lim[d];
        lim[NDOF + d]   = qdd_lim[d];
        lim[2*NDOF + d] = qddd_lim[d];
    }
    __syncthreads();

    float lqd[NDOF], lqdd[NDOF], lqddd[NDOF];
    #pragma unroll
    for (int d = 0; d < NDOF; d++) { lqd[d] = 0.f; lqdd[d] = 0.f; lqddd[d] = 0.f; }

    #pragma unroll
    for (int i = 0; i < TT / 256; i++) {
        const int t = tid + 256 * i;

        // time-spline evaluations
        const float* ntp   = Ntb  + (size_t)t * KT;
        const float* dntp  = dNtb + (size_t)t * KT;
        const float* ddntp = ddNtb + (size_t)t * KT;
        float dtau = 0.f, ddtau = 0.f, dddtau = 0.f;
        #pragma unroll
        for (int k = 0; k < KT; k++) {
            float c = tcs[k];
            dtau   += ntp[k]   * c;
            ddtau  += dntp[k]  * c;
            dddtau += ddntp[k] * c;
        }

        // q-spline evaluations (4 bases x 7 dofs)
        const float* np    = Nb    + (size_t)t * KQ;
        const float* dnp   = dNb   + (size_t)t * KQ;
        const float* ddnp  = ddNb  + (size_t)t * KQ;
        const float* dddnp = dddNb + (size_t)t * KQ;
        float aq[NDOF], a1[NDOF], a2[NDOF], a3[NDOF];
        #pragma unroll
        for (int d = 0; d < NDOF; d++) { aq[d] = 0.f; a1[d] = 0.f; a2[d] = 0.f; a3[d] = 0.f; }
        #pragma unroll
        for (int k = 0; k < KQ; k++) {
            float n0 = np[k], n1 = dnp[k], n2 = ddnp[k], n3 = dddnp[k];
            #pragma unroll
            for (int d = 0; d < NDOF; d++) {
                float c = cps[k * NDOF + d];
                aq[d] += n0 * c; a1[d] += n1 * c; a2[d] += n2 * c; a3[d] += n3 * c;
            }
        }

        const float dtau2 = dtau * dtau;
        const float dtau3 = dtau2 * dtau;
        const float dtv   = 1.0f / (dtau * (float)TT);
        dts[t] = dtv;
        out[OFF_DT + (size_t)b * TT + t] = dtv;

        const size_t base = ((size_t)b * TT + t) * NDOF;
        #pragma unroll
        for (int d = 0; d < NDOF; d++) {
            float qd   = a1[d] * dtau;
            float qdd  = a2[d] * dtau2 + ddtau * a1[d] * dtau;
            float qddd = a3[d] * dtau3 + 3.0f * a2[d] * ddtau * dtau2
                       + a1[d] * dtau2 * dddtau + a1[d] * ddtau * ddtau * dtau;
            out[OFF_Q    + base + d] = aq[d];
            out[OFF_QD   + base + d] = qd;
            out[OFF_QDD  + base + d] = qdd;
            out[OFF_QDDD + base + d] = qddd;
            out[OFF_TQ   + base + d] = 0.0f;
            lqd[d]   += hub(qd,   lim[d])          * dtv;
            lqdd[d]  += hub(qdd,  lim[NDOF + d])   * dtv;
            lqddd[d] += hub(qddd, lim[2*NDOF + d]) * dtv;
        }
    }
    __syncthreads();

    // ---- block-wide inclusive scan of dt over T for t_cumsum / t ----
    const int s4 = 4 * tid;
    float c0 = dts[s4];
    float c1 = c0 + dts[s4 + 1];
    float c2 = c1 + dts[s4 + 2];
    float c3 = c2 + dts[s4 + 3];
    seg[tid] = c3;
    __syncthreads();
    #pragma unroll
    for (int off = 1; off < 256; off <<= 1) {
        float v = 0.0f;
        if (tid >= off) v = seg[tid - off];
        __syncthreads();
        if (tid >= off) seg[tid] += v;
        __syncthreads();
    }
    const float excl  = (tid > 0) ? seg[tid - 1] : 0.0f;
    const float total = seg[255];
    {
        const size_t tb = OFF_TCUM + (size_t)b * TT + s4;
        out[tb + 0] = c0 + excl;
        out[tb + 1] = c1 + excl;
        out[tb + 2] = c2 + excl;
        out[tb + 3] = c3 + excl;
    }
    if (tid == 0) out[OFF_T + b] = total;
    if (tid < NDOF) out[OFF_TQL + (size_t)b * NDOF + tid] = 0.0f;  // torque == 0

    // ---- loss reduction: wave shuffle -> LDS -> block ----
    const int lane = tid & 63;
    const int wv   = tid >> 6;
    #pragma unroll
    for (int d = 0; d < NDOF; d++) {
        float v0 = lqd[d], v1 = lqdd[d], v2 = lqddd[d];
        #pragma unroll
        for (int off = 32; off > 0; off >>= 1) {
            v0 += __shfl_down(v0, off);
            v1 += __shfl_down(v1, off);
            v2 += __shfl_down(v2, off);
        }
        if (lane == 0) {
            wred[wv * 21 + d]            = v0;
            wred[wv * 21 + NDOF + d]     = v1;
            wred[wv * 21 + 2*NDOF + d]   = v2;
        }
    }
    __syncthreads();
    if (tid < 21) {
        float s = wred[tid] + wred[21 + tid] + wred[42 + tid] + wred[63 + tid];
        int d = tid % NDOF;
        int which = tid / NDOF;
        size_t o = (which == 0) ? OFF_QDL : (which == 1) ? OFF_QDDL : OFF_QDDDL;
        out[o + (size_t)b * NDOF + d] = s;
        wred[tid] = s;   // stash block partial for model_loss
    }
    __syncthreads();
    if (tid == 0) {
        float p = 0.f;
        #pragma unroll
        for (int j = 0; j < 21; j++) p += wred[j];
        atomicAdd(out + OFF_MODEL, p);
    }
}

extern "C" void kernel_launch(void* const* d_in, const int* in_sizes, int n_in,
                              void* d_out, int out_size, void* d_ws, size_t ws_size,
                              hipStream_t stream) {
    const float* q_cps    = (const float*)d_in[0];
    const float* t_cps    = (const float*)d_in[1];
    const float* Nb       = (const float*)d_in[2];
    const float* dNb      = (const float*)d_in[3];
    const float* ddNb     = (const float*)d_in[4];
    const float* dddNb    = (const float*)d_in[5];
    const float* Ntb      = (const float*)d_in[6];
    const float* dNtb     = (const float*)d_in[7];
    const float* ddNtb    = (const float*)d_in[8];
    const float* qd_lim   = (const float*)d_in[9];
    const float* qdd_lim  = (const float*)d_in[10];
    const float* qddd_lim = (const float*)d_in[11];
    // d_in[12] = torque_limits — unused (torque is identically zero)
    float* out = (float*)d_out;

    // model_loss is accumulated with atomicAdd — zero it first (capturable).
    hipMemsetAsync(d_out, 0, sizeof(float), stream);
    feas_main<<<dim3(BB), dim3(256), 0, stream>>>(
        q_cps, t_cps, Nb, dNb, ddNb, dddNb, Ntb, dNtb, ddNtb,
        qd_lim, qdd_lim, qddd_lim, out);
}